// Round 1
// baseline (706.756 us; speedup 1.0000x reference)
//
#include <hip/hip_runtime.h>
#include <math.h>

#define TW 4   // t-values per block (one per wave)

// Shapes: N=64, C_IN=C_OUT=64, T=300, V=25, INTER_C=16, NUM_SUBSET=3
__launch_bounds__(256, 2)
__global__ void tagc_kernel(
    const float* __restrict__ x,      // [64,64,300,25]
    const float* __restrict__ A,      // [3,25,25]
    const float* __restrict__ G,      // [3,25,25]
    const float* __restrict__ g_w,    // [3,64,64]
    const float* __restrict__ g_b,    // [3,64]
    const float* __restrict__ a_w,    // [3,16,64]
    const float* __restrict__ a_b,    // [3,16]
    const float* __restrict__ b_w,    // [3,16,64]
    const float* __restrict__ b_b,    // [3,16]
    const float* __restrict__ bn_g,
    const float* __restrict__ bn_b,
    const float* __restrict__ bn_m,
    const float* __restrict__ bn_v,
    float* __restrict__ out)
{
  __shared__ __align__(16) float Xs[TW][64][28];   // x[n,:,t,:], padded 25->28
  __shared__ float Ps[TW][16][26];
  __shared__ float Qs[TW][16][26];
  __shared__ float Ss[TW][25][26];
  __shared__ float rowm[TW][25];
  __shared__ float rowid[TW][25];
  __shared__ float sv[TW][25];
  __shared__ float colA[3][25];

  const int tid  = threadIdx.x;
  const int w    = tid >> 6;
  const int lane = tid & 63;
  const int n    = blockIdx.y;
  const int t    = blockIdx.x * TW + w;

  // colA[i][v] = sum_a (A+G)[i][a][v]
  if (tid < 3*25) {
    int i = tid / 25, v = tid - i*25;
    float s = 0.f;
    for (int a = 0; a < 25; ++a)
      s += A[(i*25 + a)*25 + v] + G[(i*25 + a)*25 + v];
    colA[i][v] = s;
  }

  // stage X = x[n,:,t,:] into LDS
  {
    const float* xb = x + ((long)n*64*300 + t)*25;
    for (int idx = lane; idx < 64*25; idx += 64) {
      int c = idx / 25, v = idx - c*25;
      Xs[w][c][v] = xb[c*7500 + v];
    }
  }
  __syncthreads();

  float accv[25];
  #pragma unroll
  for (int v = 0; v < 25; ++v) accv[v] = 0.f;

  for (int i = 0; i < 3; ++i) {
    // ---- Stage A: P = a_w X + a_b, Q = b_w X + b_b  (16x25 each) ----
    // lane -> e = lane&15; handles v = k*4 + (lane>>4), k=0..6
    {
      const int e   = lane & 15;
      const int ln4 = lane >> 4;
      const float4* aw4 = (const float4*)(a_w + i*16*64);
      const float4* bw4 = (const float4*)(b_w + i*16*64);
      float accp[7], accq[7];
      const float pb = a_b[i*16 + e];
      const float qb = b_b[i*16 + e];
      #pragma unroll
      for (int k = 0; k < 7; ++k) { accp[k] = pb; accq[k] = qb; }
      for (int c4 = 0; c4 < 16; ++c4) {
        float4 wa = aw4[e*16 + c4];
        float4 wb = bw4[e*16 + c4];
        #pragma unroll
        for (int k = 0; k < 7; ++k) {
          int v = k*4 + ln4;              // up to 27, within pad
          float x0 = Xs[w][4*c4+0][v];
          float x1 = Xs[w][4*c4+1][v];
          float x2 = Xs[w][4*c4+2][v];
          float x3 = Xs[w][4*c4+3][v];
          accp[k] += wa.x*x0 + wa.y*x1 + wa.z*x2 + wa.w*x3;
          accq[k] += wb.x*x0 + wb.y*x1 + wb.z*x2 + wb.w*x3;
        }
      }
      #pragma unroll
      for (int k = 0; k < 7; ++k) {
        int v = k*4 + ln4;
        if (v < 25) { Ps[w][e][v] = accp[k]; Qs[w][e][v] = accq[k]; }
      }
    }
    __syncthreads();

    // ---- Stage B1: Sraw[a][w'] = P[:,a].Q[:,w'] / 16 ----
    for (int k = 0; k < 10; ++k) {
      int elem = k*64 + lane;
      int e2 = elem < 625 ? elem : 0;
      int a = e2 / 25, ww = e2 - a*25;
      float acc = 0.f;
      #pragma unroll
      for (int e = 0; e < 16; ++e)
        acc += Ps[w][e][a] * Qs[w][e][ww];
      if (elem < 625) Ss[w][a][ww] = acc * 0.0625f;
    }
    __syncthreads();

    // ---- Stage B2: per-row max & 1/sum(exp) ----
    if (lane < 25) {
      float m = -1e30f;
      #pragma unroll
      for (int ww = 0; ww < 25; ++ww) m = fmaxf(m, Ss[w][lane][ww]);
      float d = 0.f;
      #pragma unroll
      for (int ww = 0; ww < 25; ++ww) d += __expf(Ss[w][lane][ww] - m);
      rowm[w][lane]  = m;
      rowid[w][lane] = 1.f / d;
    }
    __syncthreads();

    // ---- Stage B3: s[v] = colA[i][v] + sum_a softmax[a][v] ----
    if (lane < 25) {
      float s = colA[i][lane];
      #pragma unroll
      for (int a = 0; a < 25; ++a)
        s += __expf(Ss[w][a][lane] - rowm[w][a]) * rowid[w][a];
      sv[w][lane] = s;
    }
    __syncthreads();

    // ---- Stage C: accv[v] += s[v] * (g_w[i] X)[o=lane][v] ----
    {
      const float4* gw4 = (const float4*)(g_w + (i*64 + lane)*64);
      float dacc[25];
      #pragma unroll
      for (int v = 0; v < 25; ++v) dacc[v] = 0.f;
      for (int c4 = 0; c4 < 16; ++c4) {
        float4 g4 = gw4[c4];
        #pragma unroll
        for (int j = 0; j < 4; ++j) {
          float gj = (j==0) ? g4.x : (j==1) ? g4.y : (j==2) ? g4.z : g4.w;
          const float4* xr4 = (const float4*)(&Xs[w][4*c4+j][0]);
          float xr[28];
          float4* xrv = (float4*)xr;
          #pragma unroll
          for (int q = 0; q < 7; ++q) xrv[q] = xr4[q];
          #pragma unroll
          for (int v = 0; v < 25; ++v) dacc[v] += gj * xr[v];
        }
      }
      #pragma unroll
      for (int v = 0; v < 25; ++v) accv[v] += sv[w][v] * dacc[v];
    }
    // next subset's Stage A writes P/Q (already consumed), barrier follows it
  }

  // ---- Epilogue: BN + residual + ReLU; lane = o ----
  {
    const int o = lane;
    float scale = bn_g[o] * rsqrtf(bn_v[o] + 1e-5f);
    float shift = bn_b[o] - bn_m[o] * scale;
    float gbs   = g_b[o] + g_b[64 + o] + g_b[128 + o];
    float* ob = out + ((long)n*64*300 + (long)o*300 + t)*25;
    #pragma unroll
    for (int v = 0; v < 25; ++v) {
      float h = (accv[v] + gbs) * scale + shift + Xs[w][o][v];
      ob[v] = fmaxf(h, 0.f);
    }
  }
}

extern "C" void kernel_launch(void* const* d_in, const int* in_sizes, int n_in,
                              void* d_out, int out_size, void* d_ws, size_t ws_size,
                              hipStream_t stream) {
  (void)in_sizes; (void)n_in; (void)d_ws; (void)ws_size; (void)out_size;
  dim3 grid(300 / TW, 64);
  tagc_kernel<<<grid, dim3(256), 0, stream>>>(
      (const float*)d_in[0],  (const float*)d_in[1],  (const float*)d_in[2],
      (const float*)d_in[3],  (const float*)d_in[4],  (const float*)d_in[5],
      (const float*)d_in[6],  (const float*)d_in[7],  (const float*)d_in[8],
      (const float*)d_in[9],  (const float*)d_in[10], (const float*)d_in[11],
      (const float*)d_in[12], (float*)d_out);
}

// Round 2
// 452.673 us; speedup vs baseline: 1.5613x; 1.5613x over previous
//
#include <hip/hip_runtime.h>
#include <math.h>

// N=64, C_IN=C_OUT=64, T=300, V=25, INTER_C=16, NUM_SUBSET=3
// Block = (n, 7 t-values) -> 175 (t,v) columns, padded to 192 (12 N-tiles).
// All contractions over c (K=64) done with bf16 MFMA 16x16x32.

typedef __attribute__((ext_vector_type(8))) short bf8;
typedef __attribute__((ext_vector_type(4))) short bf4;
typedef __attribute__((ext_vector_type(4))) float f4;

#define TT    7
#define COLS  175
#define COLSP 192
#define XROW  72   // shorts per Xb row (144 B, 16B-aligned, ~2-way banks)
#define PQROW 56   // shorts per PQt row (112 B)
#define SROW  28

__device__ __forceinline__ short f2bf(float f) {
  union { float f; unsigned u; } v; v.f = f;
  unsigned u = v.u;
  u += 0x7fffu + ((u >> 16) & 1u);   // RNE
  return (short)(u >> 16);
}
__device__ __forceinline__ float bf2f(short s) {
  union { unsigned u; float f; } v;
  v.u = ((unsigned)(unsigned short)s) << 16;
  return v.f;
}

__launch_bounds__(256, 2)
__global__ void tagc_mfma_kernel(
    const float* __restrict__ x,      // [64,64,300,25]
    const float* __restrict__ A,      // [3,25,25]
    const float* __restrict__ G,      // [3,25,25]
    const float* __restrict__ g_w,    // [3,64,64]
    const float* __restrict__ g_b,    // [3,64]
    const float* __restrict__ a_w,    // [3,16,64]
    const float* __restrict__ a_b,    // [3,16]
    const float* __restrict__ b_w,    // [3,16,64]
    const float* __restrict__ b_b,    // [3,16]
    const float* __restrict__ bn_g,
    const float* __restrict__ bn_b,
    const float* __restrict__ bn_m,
    const float* __restrict__ bn_v,
    float* __restrict__ out)
{
  __shared__ __align__(16) short Xb[COLSP * XROW];   // [col][c] bf16, B-operand layout
  __shared__ __align__(16) short PQt[COLSP * PQROW]; // [col][0:16 P_e | 16:32 Q_e]
  __shared__ __align__(16) short Sbuf[COLS * SROW];  // [t*25+a][w] bf16
  __shared__ float sv[TT * 28];
  __shared__ float colA[3 * 25];

  const int tid  = threadIdx.x;
  const int wave = tid >> 6;
  const int lane = tid & 63;
  const int l15  = lane & 15;
  const int quad = lane >> 4;
  const int n    = blockIdx.y;
  const int t0   = blockIdx.x * TT;

  // ---- colA[i][v] = sum_a (A+G)[i][a][v] ----
  if (tid < 75) {
    int i = tid / 25, v = tid - 25 * i;
    float s = 0.f;
    for (int a = 0; a < 25; ++a)
      s += A[i * 625 + a * 25 + v] + G[i * 625 + a * 25 + v];
    colA[i * 25 + v] = s;
  }

  // ---- stage X -> Xb (bf16, [col][c]) ----
  {
    const float* xb = x + (long)n * 480000 + t0 * 25;
    for (int k = 0; k < 48; ++k) {
      int idx = k * 256 + tid;           // < 12288 = 192*64
      int c   = idx / COLSP;
      int col = idx - c * COLSP;
      int tl  = col / 25;
      float g = 0.f;
      if (col < COLS && (t0 + tl) < 300)
        g = xb[c * 7500 + col];
      Xb[col * XROW + c] = f2bf(g);
    }
  }

  float R[12][4];
  #pragma unroll
  for (int nt = 0; nt < 12; ++nt)
    #pragma unroll
    for (int r = 0; r < 4; ++r) R[nt][r] = 0.f;

  __syncthreads();

  for (int i = 0; i < 3; ++i) {
    // ================= PQ-GEMM: [32 x 64] * [64 x 192] =================
    {
      const int mt = wave & 1;                 // 0 -> P (a_w), 1 -> Q (b_w)
      const int ntbase = (wave >> 1) * 6;
      const float* W  = (mt ? b_w : a_w) + i * 1024;
      const float* Bv = (mt ? b_b : a_b) + i * 16;

      bf8 Af[2];
      #pragma unroll
      for (int kk = 0; kk < 2; ++kk) {
        const float* p = W + l15 * 64 + kk * 32 + quad * 8;
        f4 u0 = *(const f4*)p;
        f4 u1 = *(const f4*)(p + 4);
        bf8 a;
        a[0]=f2bf(u0[0]); a[1]=f2bf(u0[1]); a[2]=f2bf(u0[2]); a[3]=f2bf(u0[3]);
        a[4]=f2bf(u1[0]); a[5]=f2bf(u1[1]); a[6]=f2bf(u1[2]); a[7]=f2bf(u1[3]);
        Af[kk] = a;
      }
      float bias[4];
      #pragma unroll
      for (int r = 0; r < 4; ++r) bias[r] = Bv[quad * 4 + r];

      #pragma unroll
      for (int j = 0; j < 6; ++j) {
        int nt = ntbase + j;
        bf8 B0 = *(const bf8*)&Xb[(nt * 16 + l15) * XROW + quad * 8];
        bf8 B1 = *(const bf8*)&Xb[(nt * 16 + l15) * XROW + 32 + quad * 8];
        f4 acc = {0.f, 0.f, 0.f, 0.f};
        acc = __builtin_amdgcn_mfma_f32_16x16x32_bf16(Af[0], B0, acc, 0, 0, 0);
        acc = __builtin_amdgcn_mfma_f32_16x16x32_bf16(Af[1], B1, acc, 0, 0, 0);
        int col = nt * 16 + l15;
        bf4 w;
        #pragma unroll
        for (int r = 0; r < 4; ++r) w[r] = f2bf(acc[r] + bias[r]);
        *(bf4*)&PQt[col * PQROW + mt * 16 + quad * 4] = w;
      }
    }
    __syncthreads();

    // ================= S-GEMM: per-t S[a][w] = P^T Q / 16 ================
    // K=16 zero-padded to 32 in registers (quads 2,3 supply zeros).
    for (int tsel = wave; tsel < TT; tsel += 4) {
      #pragma unroll
      for (int am = 0; am < 2; ++am) {
        bf8 Afr = {0,0,0,0,0,0,0,0};
        if (quad < 2)
          Afr = *(const bf8*)&PQt[(tsel * 25 + am * 16 + l15) * PQROW + quad * 8];
        #pragma unroll
        for (int wm = 0; wm < 2; ++wm) {
          bf8 Bfr = {0,0,0,0,0,0,0,0};
          if (quad < 2)
            Bfr = *(const bf8*)&PQt[(tsel * 25 + wm * 16 + l15) * PQROW + 16 + quad * 8];
          f4 acc = {0.f, 0.f, 0.f, 0.f};
          acc = __builtin_amdgcn_mfma_f32_16x16x32_bf16(Afr, Bfr, acc, 0, 0, 0);
          int w = wm * 16 + l15;
          if (w < 25) {
            #pragma unroll
            for (int r = 0; r < 4; ++r) {
              int a = am * 16 + quad * 4 + r;
              if (a < 25)
                Sbuf[(tsel * 25 + a) * SROW + w] = f2bf(acc[r] * 0.0625f);
            }
          }
        }
      }
    }
    __syncthreads();

    // ================= softmax over w (rows of Sbuf) =====================
    if (tid < COLS) {
      int t = tid / 25, a = tid - 25 * t;
      short* row = &Sbuf[(t * 25 + a) * SROW];
      float s[25];
      float m = -1e30f;
      #pragma unroll
      for (int j = 0; j < 25; ++j) { s[j] = bf2f(row[j]); m = fmaxf(m, s[j]); }
      float d = 0.f;
      #pragma unroll
      for (int j = 0; j < 25; ++j) { s[j] = __expf(s[j] - m); d += s[j]; }
      float rd = 1.f / d;
      #pragma unroll
      for (int j = 0; j < 25; ++j) row[j] = f2bf(s[j] * rd);
    }
    __syncthreads();

    // ================= column sum -> sv[t][v] ============================
    if (tid < COLS) {
      int t = tid / 25, v = tid - 25 * t;
      float s = colA[i * 25 + v];
      #pragma unroll
      for (int a = 0; a < 25; ++a)
        s += bf2f(Sbuf[(t * 25 + a) * SROW + v]);
      sv[t * 28 + v] = s;
    }
    __syncthreads();

    // ================= Z-GEMM: [64 x 64] * [64 x 192], fold s ============
    {
      const int mt = wave;                     // 16 o-rows per wave
      const float* W = g_w + i * 4096;
      bf8 Af[2];
      #pragma unroll
      for (int kk = 0; kk < 2; ++kk) {
        const float* p = W + (mt * 16 + l15) * 64 + kk * 32 + quad * 8;
        f4 u0 = *(const f4*)p;
        f4 u1 = *(const f4*)(p + 4);
        bf8 a;
        a[0]=f2bf(u0[0]); a[1]=f2bf(u0[1]); a[2]=f2bf(u0[2]); a[3]=f2bf(u0[3]);
        a[4]=f2bf(u1[0]); a[5]=f2bf(u1[1]); a[6]=f2bf(u1[2]); a[7]=f2bf(u1[3]);
        Af[kk] = a;
      }
      #pragma unroll
      for (int nt = 0; nt < 12; ++nt) {
        bf8 B0 = *(const bf8*)&Xb[(nt * 16 + l15) * XROW + quad * 8];
        bf8 B1 = *(const bf8*)&Xb[(nt * 16 + l15) * XROW + 32 + quad * 8];
        f4 acc = {0.f, 0.f, 0.f, 0.f};
        acc = __builtin_amdgcn_mfma_f32_16x16x32_bf16(Af[0], B0, acc, 0, 0, 0);
        acc = __builtin_amdgcn_mfma_f32_16x16x32_bf16(Af[1], B1, acc, 0, 0, 0);
        int col  = nt * 16 + l15;
        int colc = col < COLS ? col : (COLS - 1);
        int t = colc / 25, v = colc - 25 * t;
        float sval = sv[t * 28 + v];
        #pragma unroll
        for (int r = 0; r < 4; ++r) R[nt][r] += acc[r] * sval;
      }
    }
    // no barrier needed: next writes (PQt) are not read until after the
    // PQ-GEMM barrier; sv rewrite is 3 barriers away.
  }

  // ================= epilogue: bias + BN + residual + ReLU ================
  {
    const int mt = wave;
    const int o0 = mt * 16 + quad * 4;
    float scale[4], shift[4], gbs[4];
    #pragma unroll
    for (int r = 0; r < 4; ++r) {
      int o = o0 + r;
      float sc = bn_g[o] * rsqrtf(bn_v[o] + 1e-5f);
      scale[r] = sc;
      shift[r] = bn_b[o] - bn_m[o] * sc;
      gbs[r]   = g_b[o] + g_b[64 + o] + g_b[128 + o];
    }
    float* ob = out + (long)n * 480000 + t0 * 25;
    #pragma unroll
    for (int nt = 0; nt < 12; ++nt) {
      int col = nt * 16 + l15;
      int tl  = col / 25;
      if (col < COLS && (t0 + tl) < 300) {
        bf4 res = *(const bf4*)&Xb[col * XROW + o0];
        #pragma unroll
        for (int r = 0; r < 4; ++r) {
          float h = (R[nt][r] + gbs[r]) * scale[r] + shift[r] + bf2f(res[r]);
          ob[(long)(o0 + r) * 7500 + col] = fmaxf(h, 0.f);
        }
      }
    }
  }
}

extern "C" void kernel_launch(void* const* d_in, const int* in_sizes, int n_in,
                              void* d_out, int out_size, void* d_ws, size_t ws_size,
                              hipStream_t stream) {
  (void)in_sizes; (void)n_in; (void)d_ws; (void)ws_size; (void)out_size;
  dim3 grid((300 + TT - 1) / TT, 64);   // 43 x 64
  tagc_mfma_kernel<<<grid, dim3(256), 0, stream>>>(
      (const float*)d_in[0],  (const float*)d_in[1],  (const float*)d_in[2],
      (const float*)d_in[3],  (const float*)d_in[4],  (const float*)d_in[5],
      (const float*)d_in[6],  (const float*)d_in[7],  (const float*)d_in[8],
      (const float*)d_in[9],  (const float*)d_in[10], (const float*)d_in[11],
      (const float*)d_in[12], (float*)d_out);
}

// Round 3
// 366.472 us; speedup vs baseline: 1.9285x; 1.2352x over previous
//
#include <hip/hip_runtime.h>
#include <math.h>

// N=64, C_IN=C_OUT=64, T=300, V=25, INTER_C=16, NUM_SUBSET=3
// Block = (n, 7 t-values) -> 175 (t,v) columns, padded to 192 (12 N-tiles).
// Contractions over c (K=64) via bf16 MFMA 16x16x32. Softmax + column-sum
// fully in registers via cross-lane shuffles (no S matrix in LDS).

typedef __attribute__((ext_vector_type(8))) short bf8;
typedef __attribute__((ext_vector_type(4))) short bf4;
typedef __attribute__((ext_vector_type(4))) float f4;

#define TT    7
#define COLS  175
#define COLSP 192
#define XROW  72   // shorts per Xb row (144 B)
#define PQROW 56   // shorts per PQt row (112 B)

__device__ __forceinline__ short f2bf(float f) {
  union { float f; unsigned u; } v; v.f = f;
  unsigned u = v.u;
  u += 0x7fffu + ((u >> 16) & 1u);   // RNE
  return (short)(u >> 16);
}
__device__ __forceinline__ float bf2f(short s) {
  union { unsigned u; float f; } v;
  v.u = ((unsigned)(unsigned short)s) << 16;
  return v.f;
}
__device__ __forceinline__ float rmax16(float v) {
  v = fmaxf(v, __shfl_xor(v, 1));
  v = fmaxf(v, __shfl_xor(v, 2));
  v = fmaxf(v, __shfl_xor(v, 4));
  v = fmaxf(v, __shfl_xor(v, 8));
  return v;
}
__device__ __forceinline__ float rsum16(float v) {
  v += __shfl_xor(v, 1);
  v += __shfl_xor(v, 2);
  v += __shfl_xor(v, 4);
  v += __shfl_xor(v, 8);
  return v;
}

__launch_bounds__(256, 3)
__global__ void tagc_mfma3_kernel(
    const float* __restrict__ x,      // [64,64,300,25]
    const float* __restrict__ A,      // [3,25,25]
    const float* __restrict__ G,      // [3,25,25]
    const float* __restrict__ g_w,    // [3,64,64]
    const float* __restrict__ g_b,    // [3,64]
    const float* __restrict__ a_w,    // [3,16,64]
    const float* __restrict__ a_b,    // [3,16]
    const float* __restrict__ b_w,    // [3,16,64]
    const float* __restrict__ b_b,    // [3,16]
    const float* __restrict__ bn_g,
    const float* __restrict__ bn_b,
    const float* __restrict__ bn_m,
    const float* __restrict__ bn_v,
    float* __restrict__ out)
{
  __shared__ __align__(16) short Xb[COLSP * XROW];   // [col][c] bf16
  __shared__ __align__(16) short PQt[COLSP * PQROW]; // [col][0:16 P | 16:32 Q]
  __shared__ float sv[TT * 28];
  __shared__ float colA[3 * 25];

  const int tid  = threadIdx.x;
  const int wave = tid >> 6;
  const int lane = tid & 63;
  const int l15  = lane & 15;
  const int quad = lane >> 4;
  const int n    = blockIdx.y;
  const int t0   = blockIdx.x * TT;

  // ---- colA[i][v] = sum_a (A+G)[i][a][v] ----
  if (tid < 75) {
    int i = tid / 25, v = tid - 25 * i;
    float s = 0.f;
    for (int a = 0; a < 25; ++a)
      s += A[i * 625 + a * 25 + v] + G[i * 625 + a * 25 + v];
    colA[i * 25 + v] = s;
  }

  // ---- stage X -> Xb (bf16, [col][c]), 4 c-values per thread-iter ----
  {
    const float* xb = x + (long)n * 480000 + t0 * 25;
    for (int k = 0; k < 12; ++k) {
      int idx = k * 256 + tid;          // < 3072 = 16 * 192
      int c4  = idx / COLSP;            // 0..15
      int col = idx - c4 * COLSP;       // 0..191
      int tl  = col / 25;
      bool ok = (col < COLS) && ((t0 + tl) < 300);
      bf4 wv;
      #pragma unroll
      for (int j = 0; j < 4; ++j) {
        float g = ok ? xb[(4 * c4 + j) * 7500 + col] : 0.f;
        wv[j] = f2bf(g);
      }
      *(bf4*)&Xb[col * XROW + 4 * c4] = wv;
    }
  }

  float R[12][4];
  #pragma unroll
  for (int nt = 0; nt < 12; ++nt)
    #pragma unroll
    for (int r = 0; r < 4; ++r) R[nt][r] = 0.f;

  __syncthreads();

  for (int i = 0; i < 3; ++i) {
    // ========== Phase A: PQ-GEMM [32 x 64] * [64 x 192] ==========
    {
      const int mt = wave & 1;                 // 0 -> P (a_w), 1 -> Q (b_w)
      const int ntbase = (wave >> 1) * 6;
      const float* W  = (mt ? b_w : a_w) + i * 1024;
      const float* Bv = (mt ? b_b : a_b) + i * 16;

      bf8 Af[2];
      #pragma unroll
      for (int kk = 0; kk < 2; ++kk) {
        const float* p = W + l15 * 64 + kk * 32 + quad * 8;
        f4 u0 = *(const f4*)p;
        f4 u1 = *(const f4*)(p + 4);
        bf8 a;
        a[0]=f2bf(u0[0]); a[1]=f2bf(u0[1]); a[2]=f2bf(u0[2]); a[3]=f2bf(u0[3]);
        a[4]=f2bf(u1[0]); a[5]=f2bf(u1[1]); a[6]=f2bf(u1[2]); a[7]=f2bf(u1[3]);
        Af[kk] = a;
      }
      float bias[4];
      #pragma unroll
      for (int r = 0; r < 4; ++r) bias[r] = Bv[quad * 4 + r];

      #pragma unroll
      for (int j = 0; j < 6; ++j) {
        int nt = ntbase + j;
        bf8 B0 = *(const bf8*)&Xb[(nt * 16 + l15) * XROW + quad * 8];
        bf8 B1 = *(const bf8*)&Xb[(nt * 16 + l15) * XROW + 32 + quad * 8];
        f4 acc = {0.f, 0.f, 0.f, 0.f};
        acc = __builtin_amdgcn_mfma_f32_16x16x32_bf16(Af[0], B0, acc, 0, 0, 0);
        acc = __builtin_amdgcn_mfma_f32_16x16x32_bf16(Af[1], B1, acc, 0, 0, 0);
        int col = nt * 16 + l15;
        bf4 w;
        #pragma unroll
        for (int r = 0; r < 4; ++r) w[r] = f2bf(acc[r] + bias[r]);
        *(bf4*)&PQt[col * PQROW + mt * 16 + quad * 4] = w;
      }
    }
    __syncthreads();

    // ========== Phase B: S-GEMM + in-register softmax/colsum + Z-MFMAs ====
    for (int tsel = wave; tsel < TT; tsel += 4) {
      f4 sacc[2][2];
      #pragma unroll
      for (int am = 0; am < 2; ++am) {
        bf8 Afr = {0,0,0,0,0,0,0,0};
        if (quad < 2)
          Afr = *(const bf8*)&PQt[(tsel * 25 + am * 16 + l15) * PQROW + quad * 8];
        #pragma unroll
        for (int wm = 0; wm < 2; ++wm) {
          bf8 Bfr = {0,0,0,0,0,0,0,0};
          if (quad < 2)
            Bfr = *(const bf8*)&PQt[(tsel * 25 + wm * 16 + l15) * PQROW + 16 + quad * 8];
          f4 acc = {0.f, 0.f, 0.f, 0.f};
          sacc[am][wm] = __builtin_amdgcn_mfma_f32_16x16x32_bf16(Afr, Bfr, acc, 0, 0, 0);
        }
      }
      // softmax over w per row a, plus column-sum over a, all in registers
      const bool w1ok = (l15 < 9);
      float cs0 = 0.f, cs1 = 0.f;
      #pragma unroll
      for (int am = 0; am < 2; ++am) {
        #pragma unroll
        for (int r = 0; r < 4; ++r) {
          float s0 = sacc[am][0][r] * 0.0625f;
          float s1 = sacc[am][1][r] * 0.0625f;
          float m = rmax16(fmaxf(s0, w1ok ? s1 : -1e30f));
          float e0 = __expf(s0 - m);
          float e1 = w1ok ? __expf(s1 - m) : 0.f;
          float d = rsum16(e0 + e1);
          float rd = 1.f / d;
          int a = am * 16 + quad * 4 + r;
          if (a < 25) { cs0 += e0 * rd; cs1 += e1 * rd; }
        }
      }
      cs0 += __shfl_xor(cs0, 16); cs0 += __shfl_xor(cs0, 32);
      cs1 += __shfl_xor(cs1, 16); cs1 += __shfl_xor(cs1, 32);
      if (quad == 0) {
        sv[tsel * 28 + l15] = cs0 + colA[i * 25 + l15];
        if (l15 < 9)
          sv[tsel * 28 + 16 + l15] = cs1 + colA[i * 25 + 16 + l15];
      }
    }

    // Z-MFMAs (independent of softmax): za = (g_w[i] X) tiles
    f4 za[12];
    {
      const int mt = wave;                     // 16 o-rows per wave
      const float* W = g_w + i * 4096;
      bf8 Af[2];
      #pragma unroll
      for (int kk = 0; kk < 2; ++kk) {
        const float* p = W + (mt * 16 + l15) * 64 + kk * 32 + quad * 8;
        f4 u0 = *(const f4*)p;
        f4 u1 = *(const f4*)(p + 4);
        bf8 a;
        a[0]=f2bf(u0[0]); a[1]=f2bf(u0[1]); a[2]=f2bf(u0[2]); a[3]=f2bf(u0[3]);
        a[4]=f2bf(u1[0]); a[5]=f2bf(u1[1]); a[6]=f2bf(u1[2]); a[7]=f2bf(u1[3]);
        Af[kk] = a;
      }
      #pragma unroll
      for (int nt = 0; nt < 12; ++nt) {
        bf8 B0 = *(const bf8*)&Xb[(nt * 16 + l15) * XROW + quad * 8];
        bf8 B1 = *(const bf8*)&Xb[(nt * 16 + l15) * XROW + 32 + quad * 8];
        f4 acc = {0.f, 0.f, 0.f, 0.f};
        acc = __builtin_amdgcn_mfma_f32_16x16x32_bf16(Af[0], B0, acc, 0, 0, 0);
        za[nt] = __builtin_amdgcn_mfma_f32_16x16x32_bf16(Af[1], B1, acc, 0, 0, 0);
      }
    }
    __syncthreads();

    // ========== Phase C: fold sv into R ==========
    #pragma unroll
    for (int nt = 0; nt < 12; ++nt) {
      int col  = nt * 16 + l15;
      int colc = col < COLS ? col : (COLS - 1);
      int t = colc / 25, v = colc - 25 * t;
      float sval = sv[t * 28 + v];
      #pragma unroll
      for (int r = 0; r < 4; ++r) R[nt][r] += za[nt][r] * sval;
    }
  }

  // ========== epilogue: bias + BN + residual + ReLU ==========
  {
    const int o0 = wave * 16 + quad * 4;
    float scale[4], shift[4], gbs[4];
    #pragma unroll
    for (int r = 0; r < 4; ++r) {
      int o = o0 + r;
      float sc = bn_g[o] * rsqrtf(bn_v[o] + 1e-5f);
      scale[r] = sc;
      shift[r] = bn_b[o] - bn_m[o] * sc;
      gbs[r]   = g_b[o] + g_b[64 + o] + g_b[128 + o];
    }
    float* ob = out + (long)n * 480000 + t0 * 25;
    #pragma unroll
    for (int nt = 0; nt < 12; ++nt) {
      int col = nt * 16 + l15;
      int tl  = col / 25;
      if (col < COLS && (t0 + tl) < 300) {
        bf4 res = *(const bf4*)&Xb[col * XROW + o0];
        #pragma unroll
        for (int r = 0; r < 4; ++r) {
          float h = (R[nt][r] + gbs[r]) * scale[r] + shift[r] + bf2f(res[r]);
          ob[(long)(o0 + r) * 7500 + col] = fmaxf(h, 0.f);
        }
      }
    }
  }
}

extern "C" void kernel_launch(void* const* d_in, const int* in_sizes, int n_in,
                              void* d_out, int out_size, void* d_ws, size_t ws_size,
                              hipStream_t stream) {
  (void)in_sizes; (void)n_in; (void)d_ws; (void)ws_size; (void)out_size;
  dim3 grid((300 + TT - 1) / TT, 64);   // 43 x 64
  tagc_mfma3_kernel<<<grid, dim3(256), 0, stream>>>(
      (const float*)d_in[0],  (const float*)d_in[1],  (const float*)d_in[2],
      (const float*)d_in[3],  (const float*)d_in[4],  (const float*)d_in[5],
      (const float*)d_in[6],  (const float*)d_in[7],  (const float*)d_in[8],
      (const float*)d_in[9],  (const float*)d_in[10], (const float*)d_in[11],
      (const float*)d_in[12], (float*)d_out);
}

// Round 4
// 360.224 us; speedup vs baseline: 1.9620x; 1.0173x over previous
//
#include <hip/hip_runtime.h>
#include <math.h>

// N=64, C_IN=C_OUT=64, T=300, V=25, INTER_C=16, NUM_SUBSET=3
// Block = (n, 5 t-values) -> 125 (t,v) cols, padded to 128 (8 16-tiles / 4 32-tiles).
// Phases per subset: [PQ-GEMM 16x16] bar [S-GEMM + reg-softmax -> sv] bar
// [Z-GEMM 32x32x16 + fold]. 28.8 KB LDS -> 5 blocks/CU.

typedef __attribute__((ext_vector_type(8)))  short bf8;
typedef __attribute__((ext_vector_type(4)))  short bf4;
typedef __attribute__((ext_vector_type(4)))  float f4;
typedef __attribute__((ext_vector_type(16))) float f16v;

#define TT    5
#define COLS  125
#define COLSP 128
#define XROW  72   // shorts per Xb row (mult of 8 -> 16B-aligned bf8 reads)
#define PQROW 40   // shorts per PQt row (P 0:16, Q 16:32, pad)

__device__ __forceinline__ short f2bf(float f) {
  union { float f; unsigned u; } v; v.f = f;
  unsigned u = v.u;
  u += 0x7fffu + ((u >> 16) & 1u);   // RNE
  return (short)(u >> 16);
}
__device__ __forceinline__ float bf2f(short s) {
  union { unsigned u; float f; } v;
  v.u = ((unsigned)(unsigned short)s) << 16;
  return v.f;
}
__device__ __forceinline__ float rsum16(float v) {
  v += __shfl_xor(v, 1);
  v += __shfl_xor(v, 2);
  v += __shfl_xor(v, 4);
  v += __shfl_xor(v, 8);
  return v;
}

__launch_bounds__(256, 5)
__global__ void tagc_v4_kernel(
    const float* __restrict__ x,      // [64,64,300,25]
    const float* __restrict__ A,      // [3,25,25]
    const float* __restrict__ G,      // [3,25,25]
    const float* __restrict__ g_w,    // [3,64,64]
    const float* __restrict__ g_b,    // [3,64]
    const float* __restrict__ a_w,    // [3,16,64]
    const float* __restrict__ a_b,    // [3,16]
    const float* __restrict__ b_w,    // [3,16,64]
    const float* __restrict__ b_b,    // [3,16]
    const float* __restrict__ bn_g,
    const float* __restrict__ bn_b,
    const float* __restrict__ bn_m,
    const float* __restrict__ bn_v,
    float* __restrict__ out)
{
  __shared__ __align__(16) short Xb[COLSP * XROW];   // [col][c] bf16, zero-padded cols
  __shared__ __align__(16) short PQt[COLSP * PQROW]; // [col][0:16 P | 16:32 Q]
  __shared__ float sv[TT * 28];
  __shared__ float colA[75];

  const int tid  = threadIdx.x;
  const int wave = tid >> 6;
  const int lane = tid & 63;
  const int l15  = lane & 15;
  const int quad = lane >> 4;
  const int l31  = lane & 31;
  const int hl   = lane >> 5;
  const int n    = blockIdx.y;
  const int t0   = blockIdx.x * TT;

  // colA[i][v] = sum_a (A+G)[i][a][v]
  if (tid < 75) {
    int i = tid / 25, v = tid - 25 * i;
    float s = 0.f;
    for (int a = 0; a < 25; ++a)
      s += A[i * 625 + a * 25 + v] + G[i * 625 + a * 25 + v];
    colA[i * 25 + v] = s;
  }

  // stage X -> Xb (bf16, [col][c])
  {
    const float* xb = x + (long)n * 480000 + t0 * 25;
    #pragma unroll
    for (int k = 0; k < 8; ++k) {
      int idx = k * 256 + tid;          // < 2048 = 16 * 128
      int c4  = idx >> 7;               // 0..15
      int col = idx & 127;
      bool ok = (col < COLS);
      bf4 wv;
      #pragma unroll
      for (int j = 0; j < 4; ++j) {
        float g = ok ? xb[(4 * c4 + j) * 7500 + col] : 0.f;
        wv[j] = f2bf(g);
      }
      *(bf4*)&Xb[col * XROW + 4 * c4] = wv;
    }
  }

  f16v R0, R1;
  #pragma unroll
  for (int r = 0; r < 16; ++r) { R0[r] = 0.f; R1[r] = 0.f; }

  __syncthreads();

  for (int i = 0; i < 3; ++i) {
    // ========== Phase A: PQ-GEMM [32 x 64] * [64 x 128], 16x16x32 ==========
    {
      const int mt  = wave & 1;                // 0 -> P (a_w), 1 -> Q (b_w)
      const int ntb = (wave >> 1) * 4;
      const float* W  = (mt ? b_w : a_w) + i * 1024;
      const float* Bv = (mt ? b_b : a_b) + i * 16;

      bf8 Af[2];
      #pragma unroll
      for (int kk = 0; kk < 2; ++kk) {
        const float* p = W + l15 * 64 + kk * 32 + quad * 8;
        f4 u0 = *(const f4*)p;
        f4 u1 = *(const f4*)(p + 4);
        bf8 a;
        a[0]=f2bf(u0[0]); a[1]=f2bf(u0[1]); a[2]=f2bf(u0[2]); a[3]=f2bf(u0[3]);
        a[4]=f2bf(u1[0]); a[5]=f2bf(u1[1]); a[6]=f2bf(u1[2]); a[7]=f2bf(u1[3]);
        Af[kk] = a;
      }
      float bias[4];
      #pragma unroll
      for (int r = 0; r < 4; ++r) bias[r] = Bv[quad * 4 + r];

      #pragma unroll
      for (int j = 0; j < 4; ++j) {
        int nt = ntb + j;
        bf8 B0 = *(const bf8*)&Xb[(nt * 16 + l15) * XROW + quad * 8];
        bf8 B1 = *(const bf8*)&Xb[(nt * 16 + l15) * XROW + 32 + quad * 8];
        f4 acc = {0.f, 0.f, 0.f, 0.f};
        acc = __builtin_amdgcn_mfma_f32_16x16x32_bf16(Af[0], B0, acc, 0, 0, 0);
        acc = __builtin_amdgcn_mfma_f32_16x16x32_bf16(Af[1], B1, acc, 0, 0, 0);
        int col = nt * 16 + l15;
        bf4 w;
        #pragma unroll
        for (int r = 0; r < 4; ++r) w[r] = f2bf(acc[r] + bias[r]);
        *(bf4*)&PQt[col * PQROW + mt * 16 + quad * 4] = w;
      }
    }
    __syncthreads();

    // ========== Phase B: S-GEMM + in-register softmax (no max-sub) ==========
    for (int tsel = wave; tsel < TT; tsel += 4) {
      f4 sacc[2][2];
      #pragma unroll
      for (int am = 0; am < 2; ++am) {
        bf8 Afr = {0,0,0,0,0,0,0,0};
        if (quad < 2 && (am * 16 + l15) < 25)
          Afr = *(const bf8*)&PQt[(tsel * 25 + am * 16 + l15) * PQROW + quad * 8];
        #pragma unroll
        for (int wm = 0; wm < 2; ++wm) {
          bf8 Bfr = {0,0,0,0,0,0,0,0};
          if (quad < 2 && (wm * 16 + l15) < 25)
            Bfr = *(const bf8*)&PQt[(tsel * 25 + wm * 16 + l15) * PQROW + 16 + quad * 8];
          f4 z = {0.f, 0.f, 0.f, 0.f};
          sacc[am][wm] = __builtin_amdgcn_mfma_f32_16x16x32_bf16(Afr, Bfr, z, 0, 0, 0);
        }
      }
      const bool w1ok = (l15 < 9);
      float cs0 = 0.f, cs1 = 0.f;
      #pragma unroll
      for (int am = 0; am < 2; ++am) {
        #pragma unroll
        for (int r = 0; r < 4; ++r) {
          float e0 = __expf(sacc[am][0][r] * 0.0625f);
          float e1 = w1ok ? __expf(sacc[am][1][r] * 0.0625f) : 0.f;
          float d  = rsum16(e0 + e1);
          float rd = 1.f / d;
          int a = am * 16 + quad * 4 + r;
          if (a < 25) { cs0 += e0 * rd; cs1 += e1 * rd; }
        }
      }
      cs0 += __shfl_xor(cs0, 16); cs0 += __shfl_xor(cs0, 32);
      cs1 += __shfl_xor(cs1, 16); cs1 += __shfl_xor(cs1, 32);
      if (quad == 0) {
        sv[tsel * 28 + l15] = cs0 + colA[i * 25 + l15];
        if (l15 < 9)
          sv[tsel * 28 + 16 + l15] = cs1 + colA[i * 25 + 16 + l15];
      }
    }
    __syncthreads();

    // ========== Phase C: Z-GEMM 32x32x16 + immediate fold into R ==========
    {
      const int trow = wave >> 1;   // o-tile (0: o 0..31, 1: o 32..63)
      const int tcb  = wave & 1;    // col-tiles tcb, tcb+2
      bf8 Ag[4];
      #pragma unroll
      for (int kk = 0; kk < 4; ++kk) {
        const float* p = g_w + i * 4096 + (trow * 32 + l31) * 64 + kk * 16 + hl * 8;
        f4 u0 = *(const f4*)p;
        f4 u1 = *(const f4*)(p + 4);
        bf8 a;
        a[0]=f2bf(u0[0]); a[1]=f2bf(u0[1]); a[2]=f2bf(u0[2]); a[3]=f2bf(u0[3]);
        a[4]=f2bf(u1[0]); a[5]=f2bf(u1[1]); a[6]=f2bf(u1[2]); a[7]=f2bf(u1[3]);
        Ag[kk] = a;
      }
      #pragma unroll
      for (int tix = 0; tix < 2; ++tix) {
        int colb = (tcb + tix * 2) * 32;
        f16v za;
        #pragma unroll
        for (int r = 0; r < 16; ++r) za[r] = 0.f;
        #pragma unroll
        for (int kk = 0; kk < 4; ++kk) {
          bf8 Bf = *(const bf8*)&Xb[(colb + l31) * XROW + kk * 16 + hl * 8];
          za = __builtin_amdgcn_mfma_f32_32x32x16_bf16(Ag[kk], Bf, za, 0, 0, 0);
        }
        int col  = colb + l31;
        int colc = col < COLS ? col : (COLS - 1);
        int t = colc / 25, v = colc - 25 * t;
        float sval = sv[t * 28 + v];
        if (tix == 0) {
          #pragma unroll
          for (int r = 0; r < 16; ++r) R0[r] += za[r] * sval;
        } else {
          #pragma unroll
          for (int r = 0; r < 16; ++r) R1[r] += za[r] * sval;
        }
      }
    }
    // no barrier: next Phase A writes PQt (last read before bar2); sv next
    // written in Phase B after bar1; Xb is read-only.
  }

  // ========== epilogue: bias + BN + residual + ReLU ==========
  {
    const int trow = wave >> 1;
    const int tcb  = wave & 1;
    float* obase = out + (long)n * 480000 + t0 * 25;
    #pragma unroll
    for (int rg = 0; rg < 4; ++rg) {
      int ob = trow * 32 + rg * 8 + hl * 4;   // 4 contiguous o starting here
      f4 bg = *(const f4*)(bn_g + ob);
      f4 bb = *(const f4*)(bn_b + ob);
      f4 bm = *(const f4*)(bn_m + ob);
      f4 bv = *(const f4*)(bn_v + ob);
      f4 g0 = *(const f4*)(g_b + ob);
      f4 g1 = *(const f4*)(g_b + 64 + ob);
      f4 g2 = *(const f4*)(g_b + 128 + ob);
      float scl[4], shf[4], gbs[4];
      #pragma unroll
      for (int r = 0; r < 4; ++r) {
        float sc = bg[r] * rsqrtf(bv[r] + 1e-5f);
        scl[r] = sc;
        shf[r] = bb[r] - bm[r] * sc;
        gbs[r] = g0[r] + g1[r] + g2[r];
      }
      #pragma unroll
      for (int tix = 0; tix < 2; ++tix) {
        int col = (tcb + tix * 2) * 32 + l31;
        if (col < COLS) {
          bf4 res = *(const bf4*)&Xb[col * XROW + ob];
          #pragma unroll
          for (int r = 0; r < 4; ++r) {
            float acc = tix ? R1[rg * 4 + r] : R0[rg * 4 + r];
            float h = (acc + gbs[r]) * scl[r] + shf[r] + bf2f(res[r]);
            obase[(long)(ob + r) * 7500 + col] = fmaxf(h, 0.f);
          }
        }
      }
    }
  }
}

extern "C" void kernel_launch(void* const* d_in, const int* in_sizes, int n_in,
                              void* d_out, int out_size, void* d_ws, size_t ws_size,
                              hipStream_t stream) {
  (void)in_sizes; (void)n_in; (void)d_ws; (void)ws_size; (void)out_size;
  dim3 grid(300 / TT, 64);   // 60 x 64
  tagc_v4_kernel<<<grid, dim3(256), 0, stream>>>(
      (const float*)d_in[0],  (const float*)d_in[1],  (const float*)d_in[2],
      (const float*)d_in[3],  (const float*)d_in[4],  (const float*)d_in[5],
      (const float*)d_in[6],  (const float*)d_in[7],  (const float*)d_in[8],
      (const float*)d_in[9],  (const float*)d_in[10], (const float*)d_in[11],
      (const float*)d_in[12], (float*)d_out);
}